// Round 1
// baseline (864.446 us; speedup 1.0000x reference)
//
#include <hip/hip_runtime.h>
#include <hip/hip_bf16.h>

#define NEG_SLOPE 0.2f

// ---------------------------------------------------------------- GEMM (fp32)
// C[M,Nc] = A[M,K] @ B[K,Nc].  64x64 tile, BK=16, 256 threads, 4x4 per thread.
#define BM 64
#define BN 64
#define BK 16

__global__ __launch_bounds__(256) void k_gemm(const float* __restrict__ A,
                                              const float* __restrict__ B,
                                              float* __restrict__ C,
                                              int M, int K, int Nc) {
  __shared__ __align__(16) float As[BK][BM + 4];  // [k][m], pad keeps 16B align
  __shared__ __align__(16) float Bs[BK][BN + 4];  // [k][n]
  const int t = threadIdx.x;
  const int bm = blockIdx.x * BM;
  const int bn = blockIdx.y * BN;
  const int tx = t & 15, ty = t >> 4;
  float acc[4][4] = {};

  for (int k0 = 0; k0 < K; k0 += BK) {
#pragma unroll
    for (int i = 0; i < 4; i++) {            // A tile: 64 rows x 16 k
      int idx = t + i * 256;                 // 0..1023
      int r = idx >> 4, c = idx & 15;
      int gr = bm + r;
      As[c][r] = (gr < M) ? A[(size_t)gr * K + k0 + c] : 0.f;
    }
#pragma unroll
    for (int i = 0; i < 4; i++) {            // B tile: 16 k x 64 n
      int idx = t + i * 256;
      int r = idx >> 6, c = idx & 63;
      Bs[r][c] = B[(size_t)(k0 + r) * Nc + bn + c];
    }
    __syncthreads();
#pragma unroll
    for (int kk = 0; kk < BK; kk++) {
      float4 av = *reinterpret_cast<const float4*>(&As[kk][ty * 4]);
      float4 bv = *reinterpret_cast<const float4*>(&Bs[kk][tx * 4]);
      float a[4] = {av.x, av.y, av.z, av.w};
      float b[4] = {bv.x, bv.y, bv.z, bv.w};
#pragma unroll
      for (int i = 0; i < 4; i++)
#pragma unroll
        for (int j = 0; j < 4; j++) acc[i][j] = fmaf(a[i], b[j], acc[i][j]);
    }
    __syncthreads();
  }
#pragma unroll
  for (int i = 0; i < 4; i++) {
    int gr = bm + ty * 4 + i;
    if (gr < M) {
      float4 o = {acc[i][0], acc[i][1], acc[i][2], acc[i][3]};
      *reinterpret_cast<float4*>(&C[(size_t)gr * Nc + bn + tx * 4]) = o;
    }
  }
}

// ------------------------------------------------------- per-node attn scores
// s_src[n,h] = sum_c h[n,h*64+c]*a_src[h,c]  (C=64 fixed; one wave per node)
__global__ __launch_bounds__(256) void k_scores(const float* __restrict__ h,
                                                const float* __restrict__ a_src,
                                                const float* __restrict__ a_dst,
                                                float* __restrict__ s_src,
                                                float* __restrict__ s_dst,
                                                int N, int H) {
  int n = blockIdx.x * 4 + (threadIdx.x >> 6);
  if (n >= N) return;
  int lane = threadIdx.x & 63;
  const float* hrow = h + (size_t)n * H * 64;
  for (int hd = 0; hd < H; hd++) {
    float hv = hrow[hd * 64 + lane];
    float sv = hv * a_src[hd * 64 + lane];
    float dv = hv * a_dst[hd * 64 + lane];
#pragma unroll
    for (int off = 32; off; off >>= 1) {
      sv += __shfl_xor(sv, off, 64);
      dv += __shfl_xor(dv, off, 64);
    }
    if (lane == 0) {
      s_src[(size_t)n * H + hd] = sv;
      s_dst[(size_t)n * H + hd] = dv;
    }
  }
}

// --------------------------------------------------------------- CSR building
__global__ void k_degree(const int* __restrict__ ei, int E, int Etot,
                         int* __restrict__ count) {
  int e = blockIdx.x * 256 + threadIdx.x;
  if (e >= Etot) return;
  int dst = (e < E) ? ei[E + e] : (e - E);  // self-loop tail
  atomicAdd(&count[dst], 1);
}

// single-block exclusive scan of count[0..N-1] -> row_ptr & cursor
__global__ __launch_bounds__(1024) void k_scan(const int* __restrict__ count,
                                               int* __restrict__ row_ptr,
                                               int* __restrict__ cursor, int N) {
  __shared__ int warp_sums[16];
  __shared__ int carry_s;
  const int t = threadIdx.x;
  const int lane = t & 63, wid = t >> 6;
  if (t == 0) carry_s = 0;
  __syncthreads();
  for (int base = 0; base < N; base += 1024) {
    int i = base + t;
    int v = (i < N) ? count[i] : 0;
    int x = v;
#pragma unroll
    for (int off = 1; off < 64; off <<= 1) {
      int y = __shfl_up(x, off, 64);
      if (lane >= off) x += y;
    }
    if (lane == 63) warp_sums[wid] = x;
    __syncthreads();
    if (wid == 0) {
      int s = (lane < 16) ? warp_sums[lane] : 0;
#pragma unroll
      for (int off = 1; off < 16; off <<= 1) {
        int y = __shfl_up(s, off, 64);
        if (lane >= off) s += y;
      }
      if (lane < 16) warp_sums[lane] = s;
    }
    __syncthreads();
    int woff = (wid > 0) ? warp_sums[wid - 1] : 0;
    int incl = x + woff;
    int carry = carry_s;
    if (i < N) {
      int excl = carry + incl - v;
      row_ptr[i] = excl;
      cursor[i] = excl;
    }
    __syncthreads();
    if (t == 1023) carry_s = carry + incl;  // chunk total
    __syncthreads();
  }
  if (t == 0) row_ptr[N] = carry_s;
}

__global__ void k_scatter(const int* __restrict__ ei, int E, int Etot,
                          int* __restrict__ cursor, int* __restrict__ src_sorted) {
  int e = blockIdx.x * 256 + threadIdx.x;
  if (e >= Etot) return;
  int src, dst;
  if (e < E) { src = ei[e]; dst = ei[E + e]; }
  else       { src = dst = e - E; }
  int pos = atomicAdd(&cursor[dst], 1);
  src_sorted[pos] = src;
}

// ------------------------------------------------- layer-1 aggregation (H=4)
// one wave per dst node; lane owns 4 channels (float4); alpha folded as
// (sum w*h) / (sum w); w recomputed from s_src/s_dst on the fly.
__global__ __launch_bounds__(256) void k_agg1(const float* __restrict__ h1,
                                              const int* __restrict__ row_ptr,
                                              const int* __restrict__ src_sorted,
                                              const float* __restrict__ s_src,
                                              const float* __restrict__ s_dst,
                                              const float* __restrict__ bias,
                                              float* __restrict__ out, int N) {
  int n = blockIdx.x * 4 + (threadIdx.x >> 6);
  if (n >= N) return;
  int lane = threadIdx.x & 63;
  int hd = lane >> 4;                      // 4 heads x 16 lanes
  float sdn = s_dst[(size_t)n * 4 + hd];
  int beg = row_ptr[n], end = row_ptr[n + 1];
  float4 acc = {0.f, 0.f, 0.f, 0.f};
  float wsum = 0.f;
  for (int p = beg; p < end; p++) {
    int s = src_sorted[p];
    float ee = s_src[(size_t)s * 4 + hd] + sdn;
    ee = ee > 0.f ? ee : NEG_SLOPE * ee;
    float w = expf(ee);
    float4 hv = *reinterpret_cast<const float4*>(h1 + (size_t)s * 256 + lane * 4);
    acc.x = fmaf(w, hv.x, acc.x);
    acc.y = fmaf(w, hv.y, acc.y);
    acc.z = fmaf(w, hv.z, acc.z);
    acc.w = fmaf(w, hv.w, acc.w);
    wsum += w;
  }
  float inv = 1.f / (wsum + 1e-16f);
  float4 bb = *reinterpret_cast<const float4*>(bias + lane * 4);
  float4 o;
  o.x = fmaxf(fmaf(acc.x, inv, bb.x), 0.f);
  o.y = fmaxf(fmaf(acc.y, inv, bb.y), 0.f);
  o.z = fmaxf(fmaf(acc.z, inv, bb.z), 0.f);
  o.w = fmaxf(fmaf(acc.w, inv, bb.w), 0.f);
  *reinterpret_cast<float4*>(out + (size_t)n * 256 + lane * 4) = o;
}

// ------------------------------------------------- layer-2 aggregation (H=1)
__global__ __launch_bounds__(256) void k_agg2(const float* __restrict__ h2,
                                              const int* __restrict__ row_ptr,
                                              const int* __restrict__ src_sorted,
                                              const float* __restrict__ s_src,
                                              const float* __restrict__ s_dst,
                                              const float* __restrict__ bias,
                                              float* __restrict__ out, int N) {
  int n = blockIdx.x * 4 + (threadIdx.x >> 6);
  if (n >= N) return;
  int lane = threadIdx.x & 63;
  float sdn = s_dst[n];
  int beg = row_ptr[n], end = row_ptr[n + 1];
  float acc = 0.f, wsum = 0.f;
  for (int p = beg; p < end; p++) {
    int s = src_sorted[p];
    float ee = s_src[s] + sdn;
    ee = ee > 0.f ? ee : NEG_SLOPE * ee;
    float w = expf(ee);
    acc = fmaf(w, h2[(size_t)s * 64 + lane], acc);
    wsum += w;
  }
  float o = fmaxf(acc / (wsum + 1e-16f) + bias[lane], 0.f);
  out[(size_t)n * 64 + lane] = o;
}

// ------------------------------------------------------------- output head
__global__ __launch_bounds__(256) void k_out(const float* __restrict__ h,
                                             const float* __restrict__ Wout,
                                             const float* __restrict__ bout,
                                             float* __restrict__ logits, int N) {
  int n = blockIdx.x * 4 + (threadIdx.x >> 6);
  if (n >= N) return;
  int lane = threadIdx.x & 63;
  float v = h[(size_t)n * 64 + lane] * Wout[lane];
#pragma unroll
  for (int off = 32; off; off >>= 1) v += __shfl_xor(v, off, 64);
  if (lane == 0) logits[n] = v + bout[0];
}

extern "C" void kernel_launch(void* const* d_in, const int* in_sizes, int n_in,
                              void* d_out, int out_size, void* d_ws, size_t ws_size,
                              hipStream_t stream) {
  const float* x      = (const float*)d_in[0];
  const int*   ei     = (const int*)d_in[1];
  const float* W1     = (const float*)d_in[2];
  const float* a_src1 = (const float*)d_in[3];
  const float* a_dst1 = (const float*)d_in[4];
  const float* b1     = (const float*)d_in[5];
  const float* W2     = (const float*)d_in[6];
  const float* a_src2 = (const float*)d_in[7];
  const float* a_dst2 = (const float*)d_in[8];
  const float* b2     = (const float*)d_in[9];
  const float* Wout   = (const float*)d_in[10];
  const float* bout   = (const float*)d_in[11];
  float* logits = (float*)d_out;

  const int HC1  = in_sizes[5];           // 256 = H*C
  const int C    = in_sizes[9];           // 64
  const int H    = HC1 / C;               // 4
  const int F_IN = in_sizes[2] / HC1;     // 128
  const int N    = in_sizes[0] / F_IN;    // 50000
  const int E    = in_sizes[1] / 2;       // 1.6M
  const int Etot = E + N;                 // + self loops

  char* w = (char*)d_ws;
  auto alloc = [&](size_t bytes) {
    char* p = w;
    w += (bytes + 255) & ~(size_t)255;
    return p;
  };
  float* h1      = (float*)alloc((size_t)N * HC1 * 4);
  float* hact1   = (float*)alloc((size_t)N * HC1 * 4);
  float* h2      = (float*)alloc((size_t)N * C * 4);
  float* hact2   = (float*)alloc((size_t)N * C * 4);
  float* s_src1  = (float*)alloc((size_t)N * H * 4);
  float* s_dst1  = (float*)alloc((size_t)N * H * 4);
  float* s2_src  = (float*)alloc((size_t)N * 4);
  float* s2_dst  = (float*)alloc((size_t)N * 4);
  int* count     = (int*)alloc((size_t)N * 4);
  int* cursor    = (int*)alloc((size_t)N * 4);
  int* row_ptr   = (int*)alloc((size_t)(N + 1) * 4);
  int* src_sorted= (int*)alloc((size_t)Etot * 4);

  hipMemsetAsync(count, 0, (size_t)N * 4, stream);

  // layer 1
  dim3 g1((N + BM - 1) / BM, HC1 / BN);
  k_gemm<<<g1, 256, 0, stream>>>(x, W1, h1, N, F_IN, HC1);
  k_scores<<<(N + 3) / 4, 256, 0, stream>>>(h1, a_src1, a_dst1, s_src1, s_dst1, N, H);
  k_degree<<<(Etot + 255) / 256, 256, 0, stream>>>(ei, E, Etot, count);
  k_scan<<<1, 1024, 0, stream>>>(count, row_ptr, cursor, N);
  k_scatter<<<(Etot + 255) / 256, 256, 0, stream>>>(ei, E, Etot, cursor, src_sorted);
  k_agg1<<<(N + 3) / 4, 256, 0, stream>>>(h1, row_ptr, src_sorted, s_src1, s_dst1, b1, hact1, N);

  // layer 2
  dim3 g2((N + BM - 1) / BM, C / BN);
  k_gemm<<<g2, 256, 0, stream>>>(hact1, W2, h2, N, HC1, C);
  k_scores<<<(N + 3) / 4, 256, 0, stream>>>(h2, a_src2, a_dst2, s2_src, s2_dst, N, 1);
  k_agg2<<<(N + 3) / 4, 256, 0, stream>>>(h2, row_ptr, src_sorted, s2_src, s2_dst, b2, hact2, N);

  // output head
  k_out<<<(N + 3) / 4, 256, 0, stream>>>(hact2, Wout, bout, logits, N);
}

// Round 3
// 807.611 us; speedup vs baseline: 1.0704x; 1.0704x over previous
//
#include <hip/hip_runtime.h>
#include <hip/hip_bf16.h>

#define NEG_SLOPE 0.2f

// bf16 helpers: store with RNE, load via bit-shift (exact)
__device__ __forceinline__ unsigned short f2b(float f) {
  unsigned int u = __float_as_uint(f);
  unsigned int r = (u + 0x7FFFu + ((u >> 16) & 1u)) >> 16;
  return (unsigned short)r;
}
__device__ __forceinline__ float b2f(unsigned short v) {
  return __uint_as_float(((unsigned int)v) << 16);
}

// ---------------------------------------------------------------- GEMM (fp32)
// C[M,Nc] = A[M,K] @ B[K,Nc].  64x64 tile, BK=16, 256 threads, 4x4 per thread.
#define BM 64
#define BN 64
#define BK 16

__global__ __launch_bounds__(256) void k_gemm(const float* __restrict__ A,
                                              const float* __restrict__ B,
                                              float* __restrict__ C,
                                              int M, int K, int Nc) {
  __shared__ __align__(16) float As[BK][BM + 4];
  __shared__ __align__(16) float Bs[BK][BN + 4];
  const int t = threadIdx.x;
  const int bm = blockIdx.x * BM;
  const int bn = blockIdx.y * BN;
  const int tx = t & 15, ty = t >> 4;
  float acc[4][4] = {};

  for (int k0 = 0; k0 < K; k0 += BK) {
#pragma unroll
    for (int i = 0; i < 4; i++) {
      int idx = t + i * 256;
      int r = idx >> 4, c = idx & 15;
      int gr = bm + r;
      As[c][r] = (gr < M) ? A[(size_t)gr * K + k0 + c] : 0.f;
    }
#pragma unroll
    for (int i = 0; i < 4; i++) {
      int idx = t + i * 256;
      int r = idx >> 6, c = idx & 63;
      Bs[r][c] = B[(size_t)(k0 + r) * Nc + bn + c];
    }
    __syncthreads();
#pragma unroll
    for (int kk = 0; kk < BK; kk++) {
      float4 av = *reinterpret_cast<const float4*>(&As[kk][ty * 4]);
      float4 bv = *reinterpret_cast<const float4*>(&Bs[kk][tx * 4]);
      float a[4] = {av.x, av.y, av.z, av.w};
      float b[4] = {bv.x, bv.y, bv.z, bv.w};
#pragma unroll
      for (int i = 0; i < 4; i++)
#pragma unroll
        for (int j = 0; j < 4; j++) acc[i][j] = fmaf(a[i], b[j], acc[i][j]);
    }
    __syncthreads();
  }
#pragma unroll
  for (int i = 0; i < 4; i++) {
    int gr = bm + ty * 4 + i;
    if (gr < M) {
      float4 o = {acc[i][0], acc[i][1], acc[i][2], acc[i][3]};
      *reinterpret_cast<float4*>(&C[(size_t)gr * Nc + bn + tx * 4]) = o;
    }
  }
}

// -------------------------------------------- per-head GEMM with fused epilog
// hact1[gr, h*64+c'] = relu( sum_c avgxb[gr, h*128+c]*W1[c, h*64+c'] + b1 )
// A is bf16 [M, 512] (4 heads x 128), head picked by blockIdx.z.
__global__ __launch_bounds__(256) void k_gemm_head(const unsigned short* __restrict__ Ab,
                                                   const float* __restrict__ W1,
                                                   const float* __restrict__ b1,
                                                   float* __restrict__ Cout,
                                                   int M) {
  __shared__ __align__(16) float As[BK][BM + 4];
  __shared__ __align__(16) float Bs[BK][BN + 4];
  const int t = threadIdx.x;
  const int bm = blockIdx.x * BM;
  const int h = blockIdx.z;
  const int aoff = h * 128;
  const int boff = h * 64;
  const int tx = t & 15, ty = t >> 4;
  float acc[4][4] = {};

  for (int k0 = 0; k0 < 128; k0 += BK) {
#pragma unroll
    for (int i = 0; i < 4; i++) {
      int idx = t + i * 256;
      int r = idx >> 4, c = idx & 15;
      int gr = bm + r;
      As[c][r] = (gr < M) ? b2f(Ab[(size_t)gr * 512 + aoff + k0 + c]) : 0.f;
    }
#pragma unroll
    for (int i = 0; i < 4; i++) {
      int idx = t + i * 256;
      int r = idx >> 6, c = idx & 63;
      Bs[r][c] = W1[(size_t)(k0 + r) * 256 + boff + c];
    }
    __syncthreads();
#pragma unroll
    for (int kk = 0; kk < BK; kk++) {
      float4 av = *reinterpret_cast<const float4*>(&As[kk][ty * 4]);
      float4 bv = *reinterpret_cast<const float4*>(&Bs[kk][tx * 4]);
      float a[4] = {av.x, av.y, av.z, av.w};
      float b[4] = {bv.x, bv.y, bv.z, bv.w};
#pragma unroll
      for (int i = 0; i < 4; i++)
#pragma unroll
        for (int j = 0; j < 4; j++) acc[i][j] = fmaf(a[i], b[j], acc[i][j]);
    }
    __syncthreads();
  }
  float4 bb = *reinterpret_cast<const float4*>(b1 + boff + tx * 4);
#pragma unroll
  for (int i = 0; i < 4; i++) {
    int gr = bm + ty * 4 + i;
    if (gr < M) {
      float4 o;
      o.x = fmaxf(acc[i][0] + bb.x, 0.f);
      o.y = fmaxf(acc[i][1] + bb.y, 0.f);
      o.z = fmaxf(acc[i][2] + bb.z, 0.f);
      o.w = fmaxf(acc[i][3] + bb.w, 0.f);
      *reinterpret_cast<float4*>(&Cout[(size_t)gr * 256 + boff + tx * 4]) = o;
    }
  }
}

// ----------------------------------- project W1 @ a_src/a_dst -> va[128][8]
// va[k][h]   = sum_c W1[k, h*64+c]*a_src1[h,c]   (h = 0..3)
// va[k][4+h] = sum_c W1[k, h*64+c]*a_dst1[h,c]
__global__ void k_vproj(const float* __restrict__ W1,
                        const float* __restrict__ a_src1,
                        const float* __restrict__ a_dst1,
                        float* __restrict__ va) {
  int g = blockIdx.x * 256 + threadIdx.x;  // 0..1023
  if (g >= 1024) return;
  int k = g >> 3, j = g & 7;
  int h = j & 3;
  const float* a = (j < 4) ? a_src1 : a_dst1;
  float s = 0.f;
  for (int c = 0; c < 64; c++) s += W1[(size_t)k * 256 + h * 64 + c] * a[h * 64 + c];
  va[k * 8 + j] = s;
}

// ------------------------------------- scores from x: [N,8] = x[N,128]@va
__global__ __launch_bounds__(256) void k_scores_x(const float* __restrict__ x,
                                                  const float* __restrict__ va,
                                                  float* __restrict__ s_src,
                                                  float* __restrict__ s_dst,
                                                  int N) {
  int n = blockIdx.x * 4 + (threadIdx.x >> 6);
  if (n >= N) return;
  int lane = threadIdx.x & 63;
  float x0 = x[(size_t)n * 128 + lane];
  float x1 = x[(size_t)n * 128 + 64 + lane];
  float4 vs0 = *reinterpret_cast<const float4*>(va + lane * 8);
  float4 vd0 = *reinterpret_cast<const float4*>(va + lane * 8 + 4);
  float4 vs1 = *reinterpret_cast<const float4*>(va + (lane + 64) * 8);
  float4 vd1 = *reinterpret_cast<const float4*>(va + (lane + 64) * 8 + 4);
  float rs0 = x0 * vs0.x + x1 * vs1.x, rs1 = x0 * vs0.y + x1 * vs1.y;
  float rs2 = x0 * vs0.z + x1 * vs1.z, rs3 = x0 * vs0.w + x1 * vs1.w;
  float rd0 = x0 * vd0.x + x1 * vd1.x, rd1 = x0 * vd0.y + x1 * vd1.y;
  float rd2 = x0 * vd0.z + x1 * vd1.z, rd3 = x0 * vd0.w + x1 * vd1.w;
#pragma unroll
  for (int off = 32; off; off >>= 1) {
    rs0 += __shfl_xor(rs0, off, 64); rs1 += __shfl_xor(rs1, off, 64);
    rs2 += __shfl_xor(rs2, off, 64); rs3 += __shfl_xor(rs3, off, 64);
    rd0 += __shfl_xor(rd0, off, 64); rd1 += __shfl_xor(rd1, off, 64);
    rd2 += __shfl_xor(rd2, off, 64); rd3 += __shfl_xor(rd3, off, 64);
  }
  if (lane == 0) {
    float4 ss = {rs0, rs1, rs2, rs3};
    float4 dd = {rd0, rd1, rd2, rd3};
    *reinterpret_cast<float4*>(s_src + (size_t)n * 4) = ss;
    *reinterpret_cast<float4*>(s_dst + (size_t)n * 4) = dd;
  }
}

// ------------------------------------------------------- generic scores (H=1)
__global__ __launch_bounds__(256) void k_scores(const float* __restrict__ h,
                                                const float* __restrict__ a_src,
                                                const float* __restrict__ a_dst,
                                                float* __restrict__ s_src,
                                                float* __restrict__ s_dst,
                                                int N) {
  int n = blockIdx.x * 4 + (threadIdx.x >> 6);
  if (n >= N) return;
  int lane = threadIdx.x & 63;
  float hv = h[(size_t)n * 64 + lane];
  float sv = hv * a_src[lane];
  float dv = hv * a_dst[lane];
#pragma unroll
  for (int off = 32; off; off >>= 1) {
    sv += __shfl_xor(sv, off, 64);
    dv += __shfl_xor(dv, off, 64);
  }
  if (lane == 0) {
    s_src[n] = sv;
    s_dst[n] = dv;
  }
}

// --------------------------------------------------------------- fp32 -> bf16
__global__ __launch_bounds__(256) void k_cast(const float* __restrict__ src,
                                              unsigned short* __restrict__ dst,
                                              int n8) {  // count/8
  int i = blockIdx.x * 256 + threadIdx.x;
  if (i >= n8) return;
  float4 a = *reinterpret_cast<const float4*>(src + (size_t)i * 8);
  float4 b = *reinterpret_cast<const float4*>(src + (size_t)i * 8 + 4);
  ushort4 lo = {f2b(a.x), f2b(a.y), f2b(a.z), f2b(a.w)};
  ushort4 hi = {f2b(b.x), f2b(b.y), f2b(b.z), f2b(b.w)};
  *reinterpret_cast<ushort4*>(dst + (size_t)i * 8) = lo;
  *reinterpret_cast<ushort4*>(dst + (size_t)i * 8 + 4) = hi;
}

// --------------------------------------------------------------- CSR building
__global__ void k_degree(const int* __restrict__ ei, int E, int Etot,
                         int* __restrict__ count) {
  int e = blockIdx.x * 256 + threadIdx.x;
  if (e >= Etot) return;
  int dst = (e < E) ? ei[E + e] : (e - E);
  atomicAdd(&count[dst], 1);
}

__global__ __launch_bounds__(1024) void k_scan(const int* __restrict__ count,
                                               int* __restrict__ row_ptr,
                                               int* __restrict__ cursor, int N) {
  __shared__ int warp_sums[16];
  __shared__ int carry_s;
  const int t = threadIdx.x;
  const int lane = t & 63, wid = t >> 6;
  if (t == 0) carry_s = 0;
  __syncthreads();
  for (int base = 0; base < N; base += 1024) {
    int i = base + t;
    int v = (i < N) ? count[i] : 0;
    int x = v;
#pragma unroll
    for (int off = 1; off < 64; off <<= 1) {
      int y = __shfl_up(x, off, 64);
      if (lane >= off) x += y;
    }
    if (lane == 63) warp_sums[wid] = x;
    __syncthreads();
    if (wid == 0) {
      int s = (lane < 16) ? warp_sums[lane] : 0;
#pragma unroll
      for (int off = 1; off < 16; off <<= 1) {
        int y = __shfl_up(s, off, 64);
        if (lane >= off) s += y;
      }
      if (lane < 16) warp_sums[lane] = s;
    }
    __syncthreads();
    int woff = (wid > 0) ? warp_sums[wid - 1] : 0;
    int incl = x + woff;
    int carry = carry_s;
    if (i < N) {
      int excl = carry + incl - v;
      row_ptr[i] = excl;
      cursor[i] = excl;
    }
    __syncthreads();
    if (t == 1023) carry_s = carry + incl;
    __syncthreads();
  }
  if (t == 0) row_ptr[N] = carry_s;
}

__global__ void k_scatter(const int* __restrict__ ei, int E, int Etot,
                          int* __restrict__ cursor, int* __restrict__ src_sorted) {
  int e = blockIdx.x * 256 + threadIdx.x;
  if (e >= Etot) return;
  int src, dst;
  if (e < E) { src = ei[e]; dst = ei[E + e]; }
  else       { src = dst = e - E; }
  int pos = atomicAdd(&cursor[dst], 1);
  src_sorted[pos] = src;
}

// ---------------------------- layer-1 aggregation over x (bf16), 4 heads
// avgxb[n, h*128 + c] = (sum_e w_eh * xb[src_e, c]) / (sum_e w_eh)   (bf16 out)
__global__ __launch_bounds__(256) void k_aggx(const unsigned short* __restrict__ xb,
                                              const int* __restrict__ row_ptr,
                                              const int* __restrict__ src_sorted,
                                              const float* __restrict__ s_src,
                                              const float* __restrict__ s_dst,
                                              unsigned short* __restrict__ avgxb,
                                              int N) {
  int n = blockIdx.x * 4 + (threadIdx.x >> 6);
  if (n >= N) return;
  int lane = threadIdx.x & 63;
  float4 sd = *reinterpret_cast<const float4*>(s_dst + (size_t)n * 4);
  int beg = row_ptr[n], end = row_ptr[n + 1];
  float acc[4][2] = {};
  float wsum[4] = {};
  for (int p = beg; p < end; p++) {
    int s = src_sorted[p];
    float4 ss = *reinterpret_cast<const float4*>(s_src + (size_t)s * 4);
    float e0 = ss.x + sd.x, e1 = ss.y + sd.y, e2 = ss.z + sd.z, e3 = ss.w + sd.w;
    e0 = e0 > 0.f ? e0 : NEG_SLOPE * e0;
    e1 = e1 > 0.f ? e1 : NEG_SLOPE * e1;
    e2 = e2 > 0.f ? e2 : NEG_SLOPE * e2;
    e3 = e3 > 0.f ? e3 : NEG_SLOPE * e3;
    float w0 = __expf(e0), w1 = __expf(e1), w2 = __expf(e2), w3 = __expf(e3);
    unsigned int pk = *reinterpret_cast<const unsigned int*>(xb + (size_t)s * 128 + lane * 2);
    float x0 = __uint_as_float(pk << 16);
    float x1 = __uint_as_float(pk & 0xFFFF0000u);
    acc[0][0] = fmaf(w0, x0, acc[0][0]); acc[0][1] = fmaf(w0, x1, acc[0][1]);
    acc[1][0] = fmaf(w1, x0, acc[1][0]); acc[1][1] = fmaf(w1, x1, acc[1][1]);
    acc[2][0] = fmaf(w2, x0, acc[2][0]); acc[2][1] = fmaf(w2, x1, acc[2][1]);
    acc[3][0] = fmaf(w3, x0, acc[3][0]); acc[3][1] = fmaf(w3, x1, acc[3][1]);
    wsum[0] += w0; wsum[1] += w1; wsum[2] += w2; wsum[3] += w3;
  }
#pragma unroll
  for (int h = 0; h < 4; h++) {
    float inv = 1.f / (wsum[h] + 1e-16f);
    unsigned int pk = ((unsigned int)f2b(acc[h][1] * inv) << 16) | f2b(acc[h][0] * inv);
    *reinterpret_cast<unsigned int*>(avgxb + (size_t)n * 512 + h * 128 + lane * 2) = pk;
  }
}

// -------------------- layer-2 aggregation (bf16 h2) + fused relu + out head
__global__ __launch_bounds__(256) void k_agg2(const unsigned short* __restrict__ h2b,
                                              const int* __restrict__ row_ptr,
                                              const int* __restrict__ src_sorted,
                                              const float* __restrict__ s_src,
                                              const float* __restrict__ s_dst,
                                              const float* __restrict__ bias,
                                              const float* __restrict__ Wout,
                                              const float* __restrict__ bout,
                                              float* __restrict__ logits, int N) {
  int n = blockIdx.x * 4 + (threadIdx.x >> 6);
  if (n >= N) return;
  int lane = threadIdx.x & 63;
  float sdn = s_dst[n];
  int beg = row_ptr[n], end = row_ptr[n + 1];
  float acc = 0.f, wsum = 0.f;
  for (int p = beg; p < end; p++) {
    int s = src_sorted[p];
    float ee = s_src[s] + sdn;
    ee = ee > 0.f ? ee : NEG_SLOPE * ee;
    float w = __expf(ee);
    acc = fmaf(w, b2f(h2b[(size_t)s * 64 + lane]), acc);
    wsum += w;
  }
  float o = fmaxf(acc / (wsum + 1e-16f) + bias[lane], 0.f);
  float v = o * Wout[lane];
#pragma unroll
  for (int off = 32; off; off >>= 1) v += __shfl_xor(v, off, 64);
  if (lane == 0) logits[n] = v + bout[0];
}

extern "C" void kernel_launch(void* const* d_in, const int* in_sizes, int n_in,
                              void* d_out, int out_size, void* d_ws, size_t ws_size,
                              hipStream_t stream) {
  const float* x      = (const float*)d_in[0];
  const int*   ei     = (const int*)d_in[1];
  const float* W1     = (const float*)d_in[2];
  const float* a_src1 = (const float*)d_in[3];
  const float* a_dst1 = (const float*)d_in[4];
  const float* b1     = (const float*)d_in[5];
  const float* W2     = (const float*)d_in[6];
  const float* a_src2 = (const float*)d_in[7];
  const float* a_dst2 = (const float*)d_in[8];
  const float* b2     = (const float*)d_in[9];
  const float* Wout   = (const float*)d_in[10];
  const float* bout   = (const float*)d_in[11];
  float* logits = (float*)d_out;

  const int HC1  = in_sizes[5];           // 256
  const int C    = in_sizes[9];           // 64
  const int F_IN = in_sizes[2] / HC1;     // 128
  const int N    = in_sizes[0] / F_IN;    // 50000
  const int E    = in_sizes[1] / 2;       // 1.6M
  const int Etot = E + N;

  char* w = (char*)d_ws;
  auto alloc = [&](size_t bytes) {
    char* p = w;
    w += (bytes + 255) & ~(size_t)255;
    return p;
  };
  // region A: xb (bf16 x), later reused for h2 (fp32)
  char* regA = alloc((size_t)N * 128 * sizeof(unsigned short));  // 12.8 MB
  unsigned short* xb = (unsigned short*)regA;
  float* h2 = (float*)regA;  // N*64*4 = 12.8 MB, written after xb is dead
  // region B: avgxb (bf16), later reused for h2b (bf16)
  char* regB = alloc((size_t)N * 512 * sizeof(unsigned short));  // 51.2 MB
  unsigned short* avgxb = (unsigned short*)regB;
  unsigned short* h2b = (unsigned short*)regB;  // written after avgxb is dead
  float* hact1   = (float*)alloc((size_t)N * 256 * 4);           // 51.2 MB
  float* s_src1  = (float*)alloc((size_t)N * 4 * 4);
  float* s_dst1  = (float*)alloc((size_t)N * 4 * 4);
  float* s2_src  = (float*)alloc((size_t)N * 4);
  float* s2_dst  = (float*)alloc((size_t)N * 4);
  float* va      = (float*)alloc(128 * 8 * 4);
  int* count     = (int*)alloc((size_t)N * 4);
  int* cursor    = (int*)alloc((size_t)N * 4);
  int* row_ptr   = (int*)alloc((size_t)(N + 1) * 4);
  int* src_sorted= (int*)alloc((size_t)Etot * 4);

  hipMemsetAsync(count, 0, (size_t)N * 4, stream);

  // ---- layer 1 (h1 never materialized) ----
  k_vproj<<<4, 256, 0, stream>>>(W1, a_src1, a_dst1, va);
  k_cast<<<(N * 128 / 8 + 255) / 256, 256, 0, stream>>>(x, xb, N * 128 / 8);
  k_scores_x<<<(N + 3) / 4, 256, 0, stream>>>(x, va, s_src1, s_dst1, N);
  k_degree<<<(Etot + 255) / 256, 256, 0, stream>>>(ei, E, Etot, count);
  k_scan<<<1, 1024, 0, stream>>>(count, row_ptr, cursor, N);
  k_scatter<<<(Etot + 255) / 256, 256, 0, stream>>>(ei, E, Etot, cursor, src_sorted);
  k_aggx<<<(N + 3) / 4, 256, 0, stream>>>(xb, row_ptr, src_sorted, s_src1, s_dst1, avgxb, N);
  dim3 g1((N + BM - 1) / BM, 1, 4);
  k_gemm_head<<<g1, 256, 0, stream>>>(avgxb, W1, b1, hact1, N);

  // ---- layer 2 ----
  dim3 g2((N + BM - 1) / BM, C / BN);
  k_gemm<<<g2, 256, 0, stream>>>(hact1, W2, h2, N, HC1, C);
  k_scores<<<(N + 3) / 4, 256, 0, stream>>>(h2, a_src2, a_dst2, s2_src, s2_dst, N);
  k_cast<<<(N * 64 / 8 + 255) / 256, 256, 0, stream>>>(h2, h2b, N * 64 / 8);
  k_agg2<<<(N + 3) / 4, 256, 0, stream>>>(h2b, row_ptr, src_sorted, s2_src, s2_dst,
                                          b2, Wout, bout, logits, N);
}

// Round 4
// 747.333 us; speedup vs baseline: 1.1567x; 1.0807x over previous
//
#include <hip/hip_runtime.h>
#include <hip/hip_bf16.h>

#define NEG_SLOPE 0.2f

// bf16 helpers: store with RNE, load via bit-shift (exact)
__device__ __forceinline__ unsigned short f2b(float f) {
  unsigned int u = __float_as_uint(f);
  unsigned int r = (u + 0x7FFFu + ((u >> 16) & 1u)) >> 16;
  return (unsigned short)r;
}
__device__ __forceinline__ float b2f(unsigned short v) {
  return __uint_as_float(((unsigned int)v) << 16);
}
__device__ __forceinline__ float leaky_exp(float e) {
  e = e > 0.f ? e : NEG_SLOPE * e;
  return __expf(e);
}

// ---------------------------------------------------------------- GEMM (fp32)
// C[M,Nc] = A[M,K] @ B[K,Nc].  64x64 tile, BK=16, 256 threads, 4x4 per thread.
#define BM 64
#define BN 64
#define BK 16

__global__ __launch_bounds__(256) void k_gemm(const float* __restrict__ A,
                                              const float* __restrict__ B,
                                              float* __restrict__ C,
                                              int M, int K, int Nc) {
  __shared__ __align__(16) float As[BK][BM + 4];
  __shared__ __align__(16) float Bs[BK][BN + 4];
  const int t = threadIdx.x;
  const int bm = blockIdx.x * BM;
  const int bn = blockIdx.y * BN;
  const int tx = t & 15, ty = t >> 4;
  float acc[4][4] = {};

  for (int k0 = 0; k0 < K; k0 += BK) {
#pragma unroll
    for (int i = 0; i < 4; i++) {
      int idx = t + i * 256;
      int r = idx >> 4, c = idx & 15;
      int gr = bm + r;
      As[c][r] = (gr < M) ? A[(size_t)gr * K + k0 + c] : 0.f;
    }
#pragma unroll
    for (int i = 0; i < 4; i++) {
      int idx = t + i * 256;
      int r = idx >> 6, c = idx & 63;
      Bs[r][c] = B[(size_t)(k0 + r) * Nc + bn + c];
    }
    __syncthreads();
#pragma unroll
    for (int kk = 0; kk < BK; kk++) {
      float4 av = *reinterpret_cast<const float4*>(&As[kk][ty * 4]);
      float4 bv = *reinterpret_cast<const float4*>(&Bs[kk][tx * 4]);
      float a[4] = {av.x, av.y, av.z, av.w};
      float b[4] = {bv.x, bv.y, bv.z, bv.w};
#pragma unroll
      for (int i = 0; i < 4; i++)
#pragma unroll
        for (int j = 0; j < 4; j++) acc[i][j] = fmaf(a[i], b[j], acc[i][j]);
    }
    __syncthreads();
  }
#pragma unroll
  for (int i = 0; i < 4; i++) {
    int gr = bm + ty * 4 + i;
    if (gr < M) {
      float4 o = {acc[i][0], acc[i][1], acc[i][2], acc[i][3]};
      *reinterpret_cast<float4*>(&C[(size_t)gr * Nc + bn + tx * 4]) = o;
    }
  }
}

// -------------------------------------------- per-head GEMM with fused epilog
// hact1[gr, h*64+c'] = relu( sum_c avgxb[gr, h*128+c]*W1[c, h*64+c'] + b1 )
__global__ __launch_bounds__(256) void k_gemm_head(const unsigned short* __restrict__ Ab,
                                                   const float* __restrict__ W1,
                                                   const float* __restrict__ b1,
                                                   float* __restrict__ Cout,
                                                   int M) {
  __shared__ __align__(16) float As[BK][BM + 4];
  __shared__ __align__(16) float Bs[BK][BN + 4];
  const int t = threadIdx.x;
  const int bm = blockIdx.x * BM;
  const int h = blockIdx.z;
  const int aoff = h * 128;
  const int boff = h * 64;
  const int tx = t & 15, ty = t >> 4;
  float acc[4][4] = {};

  for (int k0 = 0; k0 < 128; k0 += BK) {
#pragma unroll
    for (int i = 0; i < 4; i++) {
      int idx = t + i * 256;
      int r = idx >> 4, c = idx & 15;
      int gr = bm + r;
      As[c][r] = (gr < M) ? b2f(Ab[(size_t)gr * 512 + aoff + k0 + c]) : 0.f;
    }
#pragma unroll
    for (int i = 0; i < 4; i++) {
      int idx = t + i * 256;
      int r = idx >> 6, c = idx & 63;
      Bs[r][c] = W1[(size_t)(k0 + r) * 256 + boff + c];
    }
    __syncthreads();
#pragma unroll
    for (int kk = 0; kk < BK; kk++) {
      float4 av = *reinterpret_cast<const float4*>(&As[kk][ty * 4]);
      float4 bv = *reinterpret_cast<const float4*>(&Bs[kk][tx * 4]);
      float a[4] = {av.x, av.y, av.z, av.w};
      float b[4] = {bv.x, bv.y, bv.z, bv.w};
#pragma unroll
      for (int i = 0; i < 4; i++)
#pragma unroll
        for (int j = 0; j < 4; j++) acc[i][j] = fmaf(a[i], b[j], acc[i][j]);
    }
    __syncthreads();
  }
  float4 bb = *reinterpret_cast<const float4*>(b1 + boff + tx * 4);
#pragma unroll
  for (int i = 0; i < 4; i++) {
    int gr = bm + ty * 4 + i;
    if (gr < M) {
      float4 o;
      o.x = fmaxf(acc[i][0] + bb.x, 0.f);
      o.y = fmaxf(acc[i][1] + bb.y, 0.f);
      o.z = fmaxf(acc[i][2] + bb.z, 0.f);
      o.w = fmaxf(acc[i][3] + bb.w, 0.f);
      *reinterpret_cast<float4*>(&Cout[(size_t)gr * 256 + boff + tx * 4]) = o;
    }
  }
}

// ----------------------------------- project W1 @ a_src/a_dst -> va[128][8]
__global__ void k_vproj(const float* __restrict__ W1,
                        const float* __restrict__ a_src1,
                        const float* __restrict__ a_dst1,
                        float* __restrict__ va) {
  int g = blockIdx.x * 256 + threadIdx.x;
  if (g >= 1024) return;
  int k = g >> 3, j = g & 7;
  int h = j & 3;
  const float* a = (j < 4) ? a_src1 : a_dst1;
  float s = 0.f;
  for (int c = 0; c < 64; c++) s += W1[(size_t)k * 256 + h * 64 + c] * a[h * 64 + c];
  va[k * 8 + j] = s;
}

// ------------------------------------- scores from x: [N,8] = x[N,128]@va
__global__ __launch_bounds__(256) void k_scores_x(const float* __restrict__ x,
                                                  const float* __restrict__ va,
                                                  float* __restrict__ s_src,
                                                  float* __restrict__ s_dst,
                                                  int N) {
  int n = blockIdx.x * 4 + (threadIdx.x >> 6);
  if (n >= N) return;
  int lane = threadIdx.x & 63;
  float x0 = x[(size_t)n * 128 + lane];
  float x1 = x[(size_t)n * 128 + 64 + lane];
  float4 vs0 = *reinterpret_cast<const float4*>(va + lane * 8);
  float4 vd0 = *reinterpret_cast<const float4*>(va + lane * 8 + 4);
  float4 vs1 = *reinterpret_cast<const float4*>(va + (lane + 64) * 8);
  float4 vd1 = *reinterpret_cast<const float4*>(va + (lane + 64) * 8 + 4);
  float rs0 = x0 * vs0.x + x1 * vs1.x, rs1 = x0 * vs0.y + x1 * vs1.y;
  float rs2 = x0 * vs0.z + x1 * vs1.z, rs3 = x0 * vs0.w + x1 * vs1.w;
  float rd0 = x0 * vd0.x + x1 * vd1.x, rd1 = x0 * vd0.y + x1 * vd1.y;
  float rd2 = x0 * vd0.z + x1 * vd1.z, rd3 = x0 * vd0.w + x1 * vd1.w;
#pragma unroll
  for (int off = 32; off; off >>= 1) {
    rs0 += __shfl_xor(rs0, off, 64); rs1 += __shfl_xor(rs1, off, 64);
    rs2 += __shfl_xor(rs2, off, 64); rs3 += __shfl_xor(rs3, off, 64);
    rd0 += __shfl_xor(rd0, off, 64); rd1 += __shfl_xor(rd1, off, 64);
    rd2 += __shfl_xor(rd2, off, 64); rd3 += __shfl_xor(rd3, off, 64);
  }
  if (lane == 0) {
    float4 ss = {rs0, rs1, rs2, rs3};
    float4 dd = {rd0, rd1, rd2, rd3};
    *reinterpret_cast<float4*>(s_src + (size_t)n * 4) = ss;
    *reinterpret_cast<float4*>(s_dst + (size_t)n * 4) = dd;
  }
}

// ------------------------------------------------------- generic scores (H=1)
__global__ __launch_bounds__(256) void k_scores(const float* __restrict__ h,
                                                const float* __restrict__ a_src,
                                                const float* __restrict__ a_dst,
                                                float* __restrict__ s_src,
                                                float* __restrict__ s_dst,
                                                int N) {
  int n = blockIdx.x * 4 + (threadIdx.x >> 6);
  if (n >= N) return;
  int lane = threadIdx.x & 63;
  float hv = h[(size_t)n * 64 + lane];
  float sv = hv * a_src[lane];
  float dv = hv * a_dst[lane];
#pragma unroll
  for (int off = 32; off; off >>= 1) {
    sv += __shfl_xor(sv, off, 64);
    dv += __shfl_xor(dv, off, 64);
  }
  if (lane == 0) {
    s_src[n] = sv;
    s_dst[n] = dv;
  }
}

// --------------------------------------------------------------- fp32 -> bf16
__global__ __launch_bounds__(256) void k_cast(const float* __restrict__ src,
                                              unsigned short* __restrict__ dst,
                                              int n8) {
  int i = blockIdx.x * 256 + threadIdx.x;
  if (i >= n8) return;
  float4 a = *reinterpret_cast<const float4*>(src + (size_t)i * 8);
  float4 b = *reinterpret_cast<const float4*>(src + (size_t)i * 8 + 4);
  ushort4 lo = {f2b(a.x), f2b(a.y), f2b(a.z), f2b(a.w)};
  ushort4 hi = {f2b(b.x), f2b(b.y), f2b(b.z), f2b(b.w)};
  *reinterpret_cast<ushort4*>(dst + (size_t)i * 8) = lo;
  *reinterpret_cast<ushort4*>(dst + (size_t)i * 8 + 4) = hi;
}

// --------------------------------------------------------------- CSR building
__global__ void k_degree(const int* __restrict__ ei, int E, int Etot,
                         int* __restrict__ count) {
  int e = blockIdx.x * 256 + threadIdx.x;
  if (e >= Etot) return;
  int dst = (e < E) ? ei[E + e] : (e - E);
  atomicAdd(&count[dst], 1);
}

__global__ __launch_bounds__(1024) void k_scan(const int* __restrict__ count,
                                               int* __restrict__ row_ptr,
                                               int* __restrict__ cursor, int N) {
  __shared__ int warp_sums[16];
  __shared__ int carry_s;
  const int t = threadIdx.x;
  const int lane = t & 63, wid = t >> 6;
  if (t == 0) carry_s = 0;
  __syncthreads();
  for (int base = 0; base < N; base += 1024) {
    int i = base + t;
    int v = (i < N) ? count[i] : 0;
    int x = v;
#pragma unroll
    for (int off = 1; off < 64; off <<= 1) {
      int y = __shfl_up(x, off, 64);
      if (lane >= off) x += y;
    }
    if (lane == 63) warp_sums[wid] = x;
    __syncthreads();
    if (wid == 0) {
      int s = (lane < 16) ? warp_sums[lane] : 0;
#pragma unroll
      for (int off = 1; off < 16; off <<= 1) {
        int y = __shfl_up(s, off, 64);
        if (lane >= off) s += y;
      }
      if (lane < 16) warp_sums[lane] = s;
    }
    __syncthreads();
    int woff = (wid > 0) ? warp_sums[wid - 1] : 0;
    int incl = x + woff;
    int carry = carry_s;
    if (i < N) {
      int excl = carry + incl - v;
      row_ptr[i] = excl;
      cursor[i] = excl;
    }
    __syncthreads();
    if (t == 1023) carry_s = carry + incl;
    __syncthreads();
  }
  if (t == 0) row_ptr[N] = carry_s;
}

// ------------------- scatter + layer-1 edge weights (computed ONCE per edge)
__global__ void k_scatter(const int* __restrict__ ei, int E, int Etot,
                          int* __restrict__ cursor,
                          const float* __restrict__ s_src,
                          const float* __restrict__ s_dst,
                          int* __restrict__ src_sorted,
                          int* __restrict__ dst_sorted,
                          float4* __restrict__ w1s) {
  int e = blockIdx.x * 256 + threadIdx.x;
  if (e >= Etot) return;
  int src, dst;
  if (e < E) { src = ei[e]; dst = ei[E + e]; }
  else       { src = dst = e - E; }
  int pos = atomicAdd(&cursor[dst], 1);
  src_sorted[pos] = src;
  dst_sorted[pos] = dst;
  float4 ss = *reinterpret_cast<const float4*>(s_src + (size_t)src * 4);
  float4 sd = *reinterpret_cast<const float4*>(s_dst + (size_t)dst * 4);
  float4 w;
  w.x = leaky_exp(ss.x + sd.x);
  w.y = leaky_exp(ss.y + sd.y);
  w.z = leaky_exp(ss.z + sd.z);
  w.w = leaky_exp(ss.w + sd.w);
  w1s[pos] = w;
}

// ----------------------------------------- layer-2 edge weights (CSR order)
__global__ void k_w2(const int* __restrict__ src_sorted,
                     const int* __restrict__ dst_sorted,
                     const float* __restrict__ s2s,
                     const float* __restrict__ s2d,
                     float* __restrict__ w2s, int Etot) {
  int p = blockIdx.x * 256 + threadIdx.x;
  if (p >= Etot) return;
  w2s[p] = leaky_exp(s2s[src_sorted[p]] + s2d[dst_sorted[p]]);
}

// ---------------------------- layer-1 aggregation over x (bf16), 4 heads
// weights precomputed; inner loop = broadcast w + 1-dword gather + 8 FMA.
__global__ __launch_bounds__(256) void k_aggx(const unsigned short* __restrict__ xb,
                                              const int* __restrict__ row_ptr,
                                              const int* __restrict__ src_sorted,
                                              const float4* __restrict__ w1s,
                                              unsigned short* __restrict__ avgxb,
                                              int N) {
  int n = blockIdx.x * 4 + (threadIdx.x >> 6);
  if (n >= N) return;
  int lane = threadIdx.x & 63;
  int beg = row_ptr[n], end = row_ptr[n + 1];
  float acc[4][2] = {};
  float wsum[4] = {};
  for (int p = beg; p < end; p++) {
    int s = src_sorted[p];
    float4 w = w1s[p];
    unsigned int pk = *reinterpret_cast<const unsigned int*>(xb + (size_t)s * 128 + lane * 2);
    float x0 = __uint_as_float(pk << 16);
    float x1 = __uint_as_float(pk & 0xFFFF0000u);
    acc[0][0] = fmaf(w.x, x0, acc[0][0]); acc[0][1] = fmaf(w.x, x1, acc[0][1]);
    acc[1][0] = fmaf(w.y, x0, acc[1][0]); acc[1][1] = fmaf(w.y, x1, acc[1][1]);
    acc[2][0] = fmaf(w.z, x0, acc[2][0]); acc[2][1] = fmaf(w.z, x1, acc[2][1]);
    acc[3][0] = fmaf(w.w, x0, acc[3][0]); acc[3][1] = fmaf(w.w, x1, acc[3][1]);
    wsum[0] += w.x; wsum[1] += w.y; wsum[2] += w.z; wsum[3] += w.w;
  }
#pragma unroll
  for (int h = 0; h < 4; h++) {
    float inv = 1.f / (wsum[h] + 1e-16f);
    unsigned int pk = ((unsigned int)f2b(acc[h][1] * inv) << 16) | f2b(acc[h][0] * inv);
    *reinterpret_cast<unsigned int*>(avgxb + (size_t)n * 512 + h * 128 + lane * 2) = pk;
  }
}

// -------------------- layer-2 aggregation (bf16 h2) + fused relu + out head
__global__ __launch_bounds__(256) void k_agg2(const unsigned short* __restrict__ h2b,
                                              const int* __restrict__ row_ptr,
                                              const int* __restrict__ src_sorted,
                                              const float* __restrict__ w2s,
                                              const float* __restrict__ bias,
                                              const float* __restrict__ Wout,
                                              const float* __restrict__ bout,
                                              float* __restrict__ logits, int N) {
  int n = blockIdx.x * 4 + (threadIdx.x >> 6);
  if (n >= N) return;
  int lane = threadIdx.x & 63;
  int beg = row_ptr[n], end = row_ptr[n + 1];
  float acc = 0.f, wsum = 0.f;
  for (int p = beg; p < end; p++) {
    int s = src_sorted[p];
    float w = w2s[p];
    acc = fmaf(w, b2f(h2b[(size_t)s * 64 + lane]), acc);
    wsum += w;
  }
  float o = fmaxf(acc / (wsum + 1e-16f) + bias[lane], 0.f);
  float v = o * Wout[lane];
#pragma unroll
  for (int off = 32; off; off >>= 1) v += __shfl_xor(v, off, 64);
  if (lane == 0) logits[n] = v + bout[0];
}

extern "C" void kernel_launch(void* const* d_in, const int* in_sizes, int n_in,
                              void* d_out, int out_size, void* d_ws, size_t ws_size,
                              hipStream_t stream) {
  const float* x      = (const float*)d_in[0];
  const int*   ei     = (const int*)d_in[1];
  const float* W1     = (const float*)d_in[2];
  const float* a_src1 = (const float*)d_in[3];
  const float* a_dst1 = (const float*)d_in[4];
  const float* b1     = (const float*)d_in[5];
  const float* W2     = (const float*)d_in[6];
  const float* a_src2 = (const float*)d_in[7];
  const float* a_dst2 = (const float*)d_in[8];
  const float* b2     = (const float*)d_in[9];
  const float* Wout   = (const float*)d_in[10];
  const float* bout   = (const float*)d_in[11];
  float* logits = (float*)d_out;

  const int HC1  = in_sizes[5];           // 256
  const int C    = in_sizes[9];           // 64
  const int F_IN = in_sizes[2] / HC1;     // 128
  const int N    = in_sizes[0] / F_IN;    // 50000
  const int E    = in_sizes[1] / 2;       // 1.6M
  const int Etot = E + N;

  char* w = (char*)d_ws;
  auto alloc = [&](size_t bytes) {
    char* p = w;
    w += (bytes + 255) & ~(size_t)255;
    return p;
  };
  // region A: xb (bf16 x), later reused for h2 (fp32)
  char* regA = alloc((size_t)N * 128 * sizeof(unsigned short));  // 12.8 MB
  unsigned short* xb = (unsigned short*)regA;
  float* h2 = (float*)regA;  // written after xb is dead
  // region B: avgxb (bf16); after gemm_head it is dead -> h2b at offset 0,
  // w2s at offset N*256*2 (25.6 MB), both fit without overlap.
  char* regB = alloc((size_t)N * 512 * sizeof(unsigned short));  // 51.2 MB
  unsigned short* avgxb = (unsigned short*)regB;
  unsigned short* h2b = (unsigned short*)regB;
  float* w2s = (float*)(regB + (size_t)N * 256 * sizeof(unsigned short));
  // hact1 region doubles as w1s (26.4 MB <= 51.2 MB): w1s is dead before
  // k_gemm_head writes hact1.
  char* regC = alloc((size_t)N * 256 * 4);                       // 51.2 MB
  float* hact1 = (float*)regC;
  float4* w1s = (float4*)regC;
  float* s_src1  = (float*)alloc((size_t)N * 4 * 4);
  float* s_dst1  = (float*)alloc((size_t)N * 4 * 4);
  float* s2_src  = (float*)alloc((size_t)N * 4);
  float* s2_dst  = (float*)alloc((size_t)N * 4);
  float* va      = (float*)alloc(128 * 8 * 4);
  int* count     = (int*)alloc((size_t)N * 4);
  int* cursor    = (int*)alloc((size_t)N * 4);
  int* row_ptr   = (int*)alloc((size_t)(N + 1) * 4);
  int* src_sorted= (int*)alloc((size_t)Etot * 4);
  int* dst_sorted= (int*)alloc((size_t)Etot * 4);

  hipMemsetAsync(count, 0, (size_t)N * 4, stream);

  // ---- layer 1 (h1 never materialized) ----
  k_vproj<<<4, 256, 0, stream>>>(W1, a_src1, a_dst1, va);
  k_cast<<<(N * 128 / 8 + 255) / 256, 256, 0, stream>>>(x, xb, N * 128 / 8);
  k_scores_x<<<(N + 3) / 4, 256, 0, stream>>>(x, va, s_src1, s_dst1, N);
  k_degree<<<(Etot + 255) / 256, 256, 0, stream>>>(ei, E, Etot, count);
  k_scan<<<1, 1024, 0, stream>>>(count, row_ptr, cursor, N);
  k_scatter<<<(Etot + 255) / 256, 256, 0, stream>>>(ei, E, Etot, cursor,
                                                    s_src1, s_dst1,
                                                    src_sorted, dst_sorted, w1s);
  k_aggx<<<(N + 3) / 4, 256, 0, stream>>>(xb, row_ptr, src_sorted, w1s, avgxb, N);
  dim3 g1((N + BM - 1) / BM, 1, 4);
  k_gemm_head<<<g1, 256, 0, stream>>>(avgxb, W1, b1, hact1, N);

  // ---- layer 2 ----
  dim3 g2((N + BM - 1) / BM, C / BN);
  k_gemm<<<g2, 256, 0, stream>>>(hact1, W2, h2, N, HC1, C);
  k_scores<<<(N + 3) / 4, 256, 0, stream>>>(h2, a_src2, a_dst2, s2_src, s2_dst, N);
  k_w2<<<(Etot + 255) / 256, 256, 0, stream>>>(src_sorted, dst_sorted,
                                               s2_src, s2_dst, w2s, Etot);
  k_cast<<<(N * 64 / 8 + 255) / 256, 256, 0, stream>>>(h2, h2b, N * 64 / 8);
  k_agg2<<<(N + 3) / 4, 256, 0, stream>>>(h2b, row_ptr, src_sorted, w2s,
                                          b2, Wout, bout, logits, N);
}

// Round 5
// 583.877 us; speedup vs baseline: 1.4805x; 1.2799x over previous
//
#include <hip/hip_runtime.h>
#include <hip/hip_bf16.h>

#define NEG_SLOPE 0.2f

// bf16 helpers: store with RNE, load via bit-shift (exact)
__device__ __forceinline__ unsigned short f2b(float f) {
  unsigned int u = __float_as_uint(f);
  unsigned int r = (u + 0x7FFFu + ((u >> 16) & 1u)) >> 16;
  return (unsigned short)r;
}
__device__ __forceinline__ float b2f(unsigned short v) {
  return __uint_as_float(((unsigned int)v) << 16);
}
__device__ __forceinline__ float leaky_exp(float e) {
  e = e > 0.f ? e : NEG_SLOPE * e;
  return __expf(e);
}

#define BM 64
#define BN 64
#define BK 16

// ------------------------------ layer-2 GEMM: h2b[M,64] = hact1[M,256] @ W2
// fp32 in, bf16 out (fused cast). Nc=64 fixed, K=256 fixed.
__global__ __launch_bounds__(256) void k_gemm2(const float* __restrict__ A,
                                               const float* __restrict__ B,
                                               unsigned short* __restrict__ Cb,
                                               int M) {
  __shared__ __align__(16) float As[BK][BM + 4];
  __shared__ __align__(16) float Bs[BK][BN + 4];
  const int t = threadIdx.x;
  const int bm = blockIdx.x * BM;
  const int tx = t & 15, ty = t >> 4;
  float acc[4][4] = {};

  for (int k0 = 0; k0 < 256; k0 += BK) {
#pragma unroll
    for (int i = 0; i < 4; i++) {
      int idx = t + i * 256;
      int r = idx >> 4, c = idx & 15;
      int gr = bm + r;
      As[c][r] = (gr < M) ? A[(size_t)gr * 256 + k0 + c] : 0.f;
    }
#pragma unroll
    for (int i = 0; i < 4; i++) {
      int idx = t + i * 256;
      int r = idx >> 6, c = idx & 63;
      Bs[r][c] = B[(size_t)(k0 + r) * 64 + c];
    }
    __syncthreads();
#pragma unroll
    for (int kk = 0; kk < BK; kk++) {
      float4 av = *reinterpret_cast<const float4*>(&As[kk][ty * 4]);
      float4 bv = *reinterpret_cast<const float4*>(&Bs[kk][tx * 4]);
      float a[4] = {av.x, av.y, av.z, av.w};
      float b[4] = {bv.x, bv.y, bv.z, bv.w};
#pragma unroll
      for (int i = 0; i < 4; i++)
#pragma unroll
        for (int j = 0; j < 4; j++) acc[i][j] = fmaf(a[i], b[j], acc[i][j]);
    }
    __syncthreads();
  }
#pragma unroll
  for (int i = 0; i < 4; i++) {
    int gr = bm + ty * 4 + i;
    if (gr < M) {
      ushort4 o = {f2b(acc[i][0]), f2b(acc[i][1]), f2b(acc[i][2]), f2b(acc[i][3])};
      *reinterpret_cast<ushort4*>(&Cb[(size_t)gr * 64 + tx * 4]) = o;
    }
  }
}

// -------------------------------------------- per-head GEMM with fused epilog
// hact1[gr, h*64+c'] = relu( sum_c avgxb[gr, h*128+c]*W1[c, h*64+c'] + b1 )
__global__ __launch_bounds__(256) void k_gemm_head(const unsigned short* __restrict__ Ab,
                                                   const float* __restrict__ W1,
                                                   const float* __restrict__ b1,
                                                   float* __restrict__ Cout,
                                                   int M) {
  __shared__ __align__(16) float As[BK][BM + 4];
  __shared__ __align__(16) float Bs[BK][BN + 4];
  const int t = threadIdx.x;
  const int bm = blockIdx.x * BM;
  const int h = blockIdx.z;
  const int aoff = h * 128;
  const int boff = h * 64;
  const int tx = t & 15, ty = t >> 4;
  float acc[4][4] = {};

  // A staging: vectorized ushort4 (4 bf16 per load); thread t -> row t>>2,
  // k-group (t&3)*4.
  const int ar = t >> 2;
  const int akg = (t & 3) * 4;
  const int agr = bm + ar;

  for (int k0 = 0; k0 < 128; k0 += BK) {
    ushort4 av4 = {0, 0, 0, 0};
    if (agr < M)
      av4 = *reinterpret_cast<const ushort4*>(Ab + (size_t)agr * 512 + aoff + k0 + akg);
    As[akg + 0][ar] = b2f(av4.x);
    As[akg + 1][ar] = b2f(av4.y);
    As[akg + 2][ar] = b2f(av4.z);
    As[akg + 3][ar] = b2f(av4.w);
#pragma unroll
    for (int i = 0; i < 4; i++) {
      int idx = t + i * 256;
      int r = idx >> 6, c = idx & 63;
      Bs[r][c] = W1[(size_t)(k0 + r) * 256 + boff + c];
    }
    __syncthreads();
#pragma unroll
    for (int kk = 0; kk < BK; kk++) {
      float4 av = *reinterpret_cast<const float4*>(&As[kk][ty * 4]);
      float4 bv = *reinterpret_cast<const float4*>(&Bs[kk][tx * 4]);
      float a[4] = {av.x, av.y, av.z, av.w};
      float b[4] = {bv.x, bv.y, bv.z, bv.w};
#pragma unroll
      for (int i = 0; i < 4; i++)
#pragma unroll
        for (int j = 0; j < 4; j++) acc[i][j] = fmaf(a[i], b[j], acc[i][j]);
    }
    __syncthreads();
  }
  float4 bb = *reinterpret_cast<const float4*>(b1 + boff + tx * 4);
#pragma unroll
  for (int i = 0; i < 4; i++) {
    int gr = bm + ty * 4 + i;
    if (gr < M) {
      float4 o;
      o.x = fmaxf(acc[i][0] + bb.x, 0.f);
      o.y = fmaxf(acc[i][1] + bb.y, 0.f);
      o.z = fmaxf(acc[i][2] + bb.z, 0.f);
      o.w = fmaxf(acc[i][3] + bb.w, 0.f);
      *reinterpret_cast<float4*>(&Cout[(size_t)gr * 256 + boff + tx * 4]) = o;
    }
  }
}

// ----------------------------------- project W1 @ a_src/a_dst -> va[128][8]
__global__ void k_vproj(const float* __restrict__ W1,
                        const float* __restrict__ a_src1,
                        const float* __restrict__ a_dst1,
                        float* __restrict__ va) {
  int g = blockIdx.x * 256 + threadIdx.x;
  if (g >= 1024) return;
  int k = g >> 3, j = g & 7;
  int h = j & 3;
  const float* a = (j < 4) ? a_src1 : a_dst1;
  float s = 0.f;
  for (int c = 0; c < 64; c++) s += W1[(size_t)k * 256 + h * 64 + c] * a[h * 64 + c];
  va[k * 8 + j] = s;
}

// ------------------------------------- scores from x: [N,8] = x[N,128]@va
__global__ __launch_bounds__(256) void k_scores_x(const float* __restrict__ x,
                                                  const float* __restrict__ va,
                                                  float* __restrict__ s_src,
                                                  float* __restrict__ s_dst,
                                                  int N) {
  int n = blockIdx.x * 4 + (threadIdx.x >> 6);
  if (n >= N) return;
  int lane = threadIdx.x & 63;
  float x0 = x[(size_t)n * 128 + lane];
  float x1 = x[(size_t)n * 128 + 64 + lane];
  float4 vs0 = *reinterpret_cast<const float4*>(va + lane * 8);
  float4 vd0 = *reinterpret_cast<const float4*>(va + lane * 8 + 4);
  float4 vs1 = *reinterpret_cast<const float4*>(va + (lane + 64) * 8);
  float4 vd1 = *reinterpret_cast<const float4*>(va + (lane + 64) * 8 + 4);
  float rs0 = x0 * vs0.x + x1 * vs1.x, rs1 = x0 * vs0.y + x1 * vs1.y;
  float rs2 = x0 * vs0.z + x1 * vs1.z, rs3 = x0 * vs0.w + x1 * vs1.w;
  float rd0 = x0 * vd0.x + x1 * vd1.x, rd1 = x0 * vd0.y + x1 * vd1.y;
  float rd2 = x0 * vd0.z + x1 * vd1.z, rd3 = x0 * vd0.w + x1 * vd1.w;
#pragma unroll
  for (int off = 32; off; off >>= 1) {
    rs0 += __shfl_xor(rs0, off, 64); rs1 += __shfl_xor(rs1, off, 64);
    rs2 += __shfl_xor(rs2, off, 64); rs3 += __shfl_xor(rs3, off, 64);
    rd0 += __shfl_xor(rd0, off, 64); rd1 += __shfl_xor(rd1, off, 64);
    rd2 += __shfl_xor(rd2, off, 64); rd3 += __shfl_xor(rd3, off, 64);
  }
  if (lane == 0) {
    float4 ss = {rs0, rs1, rs2, rs3};
    float4 dd = {rd0, rd1, rd2, rd3};
    *reinterpret_cast<float4*>(s_src + (size_t)n * 4) = ss;
    *reinterpret_cast<float4*>(s_dst + (size_t)n * 4) = dd;
  }
}

// ------------------------------------------- scores for layer 2 (bf16 input)
__global__ __launch_bounds__(256) void k_scores2(const unsigned short* __restrict__ h2b,
                                                 const float* __restrict__ a_src,
                                                 const float* __restrict__ a_dst,
                                                 float* __restrict__ s_src,
                                                 float* __restrict__ s_dst,
                                                 int N) {
  int n = blockIdx.x * 4 + (threadIdx.x >> 6);
  if (n >= N) return;
  int lane = threadIdx.x & 63;
  float hv = b2f(h2b[(size_t)n * 64 + lane]);
  float sv = hv * a_src[lane];
  float dv = hv * a_dst[lane];
#pragma unroll
  for (int off = 32; off; off >>= 1) {
    sv += __shfl_xor(sv, off, 64);
    dv += __shfl_xor(dv, off, 64);
  }
  if (lane == 0) {
    s_src[n] = sv;
    s_dst[n] = dv;
  }
}

// --------------------------------------------------------------- fp32 -> bf16
__global__ __launch_bounds__(256) void k_cast(const float* __restrict__ src,
                                              unsigned short* __restrict__ dst,
                                              int n8) {
  int i = blockIdx.x * 256 + threadIdx.x;
  if (i >= n8) return;
  float4 a = *reinterpret_cast<const float4*>(src + (size_t)i * 8);
  float4 b = *reinterpret_cast<const float4*>(src + (size_t)i * 8 + 4);
  ushort4 lo = {f2b(a.x), f2b(a.y), f2b(a.z), f2b(a.w)};
  ushort4 hi = {f2b(b.x), f2b(b.y), f2b(b.z), f2b(b.w)};
  *reinterpret_cast<ushort4*>(dst + (size_t)i * 8) = lo;
  *reinterpret_cast<ushort4*>(dst + (size_t)i * 8 + 4) = hi;
}

// --------------------------------------------------------------- CSR building
__global__ void k_degree(const int* __restrict__ ei, int E, int Etot,
                         int* __restrict__ count) {
  int e = blockIdx.x * 256 + threadIdx.x;
  if (e >= Etot) return;
  int dst = (e < E) ? ei[E + e] : (e - E);
  atomicAdd(&count[dst], 1);
}

__global__ __launch_bounds__(1024) void k_scan(const int* __restrict__ count,
                                               int* __restrict__ row_ptr,
                                               int* __restrict__ cursor, int N) {
  __shared__ int warp_sums[16];
  __shared__ int carry_s;
  const int t = threadIdx.x;
  const int lane = t & 63, wid = t >> 6;
  if (t == 0) carry_s = 0;
  __syncthreads();
  for (int base = 0; base < N; base += 1024) {
    int i = base + t;
    int v = (i < N) ? count[i] : 0;
    int x = v;
#pragma unroll
    for (int off = 1; off < 64; off <<= 1) {
      int y = __shfl_up(x, off, 64);
      if (lane >= off) x += y;
    }
    if (lane == 63) warp_sums[wid] = x;
    __syncthreads();
    if (wid == 0) {
      int s = (lane < 16) ? warp_sums[lane] : 0;
#pragma unroll
      for (int off = 1; off < 16; off <<= 1) {
        int y = __shfl_up(s, off, 64);
        if (lane >= off) s += y;
      }
      if (lane < 16) warp_sums[lane] = s;
    }
    __syncthreads();
    int woff = (wid > 0) ? warp_sums[wid - 1] : 0;
    int incl = x + woff;
    int carry = carry_s;
    if (i < N) {
      int excl = carry + incl - v;
      row_ptr[i] = excl;
      cursor[i] = excl;
    }
    __syncthreads();
    if (t == 1023) carry_s = carry + incl;
    __syncthreads();
  }
  if (t == 0) row_ptr[N] = carry_s;
}

// ------------------- scatter + layer-1 edge weights (computed ONCE per edge)
__global__ void k_scatter(const int* __restrict__ ei, int E, int Etot,
                          int* __restrict__ cursor,
                          const float* __restrict__ s_src,
                          const float* __restrict__ s_dst,
                          int* __restrict__ src_sorted,
                          int* __restrict__ dst_sorted,
                          float4* __restrict__ w1s) {
  int e = blockIdx.x * 256 + threadIdx.x;
  if (e >= Etot) return;
  int src, dst;
  if (e < E) { src = ei[e]; dst = ei[E + e]; }
  else       { src = dst = e - E; }
  int pos = atomicAdd(&cursor[dst], 1);
  src_sorted[pos] = src;
  dst_sorted[pos] = dst;
  float4 ss = *reinterpret_cast<const float4*>(s_src + (size_t)src * 4);
  float4 sd = *reinterpret_cast<const float4*>(s_dst + (size_t)dst * 4);
  float4 w;
  w.x = leaky_exp(ss.x + sd.x);
  w.y = leaky_exp(ss.y + sd.y);
  w.z = leaky_exp(ss.z + sd.z);
  w.w = leaky_exp(ss.w + sd.w);
  w1s[pos] = w;
}

// ----------------------------------------- layer-2 edge weights (CSR order)
__global__ void k_w2(const int* __restrict__ src_sorted,
                     const int* __restrict__ dst_sorted,
                     const float* __restrict__ s2s,
                     const float* __restrict__ s2d,
                     float* __restrict__ w2s, int Etot) {
  int p = blockIdx.x * 256 + threadIdx.x;
  if (p >= Etot) return;
  w2s[p] = leaky_exp(s2s[src_sorted[p]] + s2d[dst_sorted[p]]);
}

// ---------------------------- layer-1 aggregation over x (bf16), 4 heads
// unroll x4: 4 independent gathers in flight per wave (MLP).
__global__ __launch_bounds__(256) void k_aggx(const unsigned short* __restrict__ xb,
                                              const int* __restrict__ row_ptr,
                                              const int* __restrict__ src_sorted,
                                              const float4* __restrict__ w1s,
                                              unsigned short* __restrict__ avgxb,
                                              int N) {
  int n = blockIdx.x * 4 + (threadIdx.x >> 6);
  if (n >= N) return;
  int lane = threadIdx.x & 63;
  int beg = row_ptr[n], end = row_ptr[n + 1];
  float acc[4][2] = {};
  float wsum[4] = {};
  int p = beg;
  for (; p + 4 <= end; p += 4) {
    int s[4];
    float4 w[4];
    unsigned int pk[4];
#pragma unroll
    for (int j = 0; j < 4; j++) s[j] = src_sorted[p + j];
#pragma unroll
    for (int j = 0; j < 4; j++) w[j] = w1s[p + j];
#pragma unroll
    for (int j = 0; j < 4; j++)
      pk[j] = *reinterpret_cast<const unsigned int*>(xb + (size_t)s[j] * 128 + lane * 2);
#pragma unroll
    for (int j = 0; j < 4; j++) {
      float x0 = __uint_as_float(pk[j] << 16);
      float x1 = __uint_as_float(pk[j] & 0xFFFF0000u);
      acc[0][0] = fmaf(w[j].x, x0, acc[0][0]); acc[0][1] = fmaf(w[j].x, x1, acc[0][1]);
      acc[1][0] = fmaf(w[j].y, x0, acc[1][0]); acc[1][1] = fmaf(w[j].y, x1, acc[1][1]);
      acc[2][0] = fmaf(w[j].z, x0, acc[2][0]); acc[2][1] = fmaf(w[j].z, x1, acc[2][1]);
      acc[3][0] = fmaf(w[j].w, x0, acc[3][0]); acc[3][1] = fmaf(w[j].w, x1, acc[3][1]);
      wsum[0] += w[j].x; wsum[1] += w[j].y; wsum[2] += w[j].z; wsum[3] += w[j].w;
    }
  }
  for (; p < end; p++) {
    int s = src_sorted[p];
    float4 w = w1s[p];
    unsigned int pk = *reinterpret_cast<const unsigned int*>(xb + (size_t)s * 128 + lane * 2);
    float x0 = __uint_as_float(pk << 16);
    float x1 = __uint_as_float(pk & 0xFFFF0000u);
    acc[0][0] = fmaf(w.x, x0, acc[0][0]); acc[0][1] = fmaf(w.x, x1, acc[0][1]);
    acc[1][0] = fmaf(w.y, x0, acc[1][0]); acc[1][1] = fmaf(w.y, x1, acc[1][1]);
    acc[2][0] = fmaf(w.z, x0, acc[2][0]); acc[2][1] = fmaf(w.z, x1, acc[2][1]);
    acc[3][0] = fmaf(w.w, x0, acc[3][0]); acc[3][1] = fmaf(w.w, x1, acc[3][1]);
    wsum[0] += w.x; wsum[1] += w.y; wsum[2] += w.z; wsum[3] += w.w;
  }
#pragma unroll
  for (int h = 0; h < 4; h++) {
    float inv = 1.f / (wsum[h] + 1e-16f);
    unsigned int pk = ((unsigned int)f2b(acc[h][1] * inv) << 16) | f2b(acc[h][0] * inv);
    *reinterpret_cast<unsigned int*>(avgxb + (size_t)n * 512 + h * 128 + lane * 2) = pk;
  }
}

// -------------------- layer-2 aggregation (bf16 h2) + fused relu + out head
// unroll x8 for MLP.
__global__ __launch_bounds__(256) void k_agg2(const unsigned short* __restrict__ h2b,
                                              const int* __restrict__ row_ptr,
                                              const int* __restrict__ src_sorted,
                                              const float* __restrict__ w2s,
                                              const float* __restrict__ bias,
                                              const float* __restrict__ Wout,
                                              const float* __restrict__ bout,
                                              float* __restrict__ logits, int N) {
  int n = blockIdx.x * 4 + (threadIdx.x >> 6);
  if (n >= N) return;
  int lane = threadIdx.x & 63;
  int beg = row_ptr[n], end = row_ptr[n + 1];
  float acc = 0.f, wsum = 0.f;
  int p = beg;
  for (; p + 8 <= end; p += 8) {
    int s[8];
    float w[8];
    unsigned short hv[8];
#pragma unroll
    for (int j = 0; j < 8; j++) s[j] = src_sorted[p + j];
#pragma unroll
    for (int j = 0; j < 8; j++) w[j] = w2s[p + j];
#pragma unroll
    for (int j = 0; j < 8; j++) hv[j] = h2b[(size_t)s[j] * 64 + lane];
#pragma unroll
    for (int j = 0; j < 8; j++) {
      acc = fmaf(w[j], b2f(hv[j]), acc);
      wsum += w[j];
    }
  }
  for (; p < end; p++) {
    float w = w2s[p];
    acc = fmaf(w, b2f(h2b[(size_t)src_sorted[p] * 64 + lane]), acc);
    wsum += w;
  }
  float o = fmaxf(acc / (wsum + 1e-16f) + bias[lane], 0.f);
  float v = o * Wout[lane];
#pragma unroll
  for (int off = 32; off; off >>= 1) v += __shfl_xor(v, off, 64);
  if (lane == 0) logits[n] = v + bout[0];
}

extern "C" void kernel_launch(void* const* d_in, const int* in_sizes, int n_in,
                              void* d_out, int out_size, void* d_ws, size_t ws_size,
                              hipStream_t stream) {
  const float* x      = (const float*)d_in[0];
  const int*   ei     = (const int*)d_in[1];
  const float* W1     = (const float*)d_in[2];
  const float* a_src1 = (const float*)d_in[3];
  const float* a_dst1 = (const float*)d_in[4];
  const float* b1     = (const float*)d_in[5];
  const float* W2     = (const float*)d_in[6];
  const float* a_src2 = (const float*)d_in[7];
  const float* a_dst2 = (const float*)d_in[8];
  const float* b2     = (const float*)d_in[9];
  const float* Wout   = (const float*)d_in[10];
  const float* bout   = (const float*)d_in[11];
  float* logits = (float*)d_out;

  const int HC1  = in_sizes[5];           // 256
  const int F_IN = in_sizes[2] / HC1;     // 128
  const int N    = in_sizes[0] / F_IN;    // 50000
  const int E    = in_sizes[1] / 2;       // 1.6M
  const int Etot = E + N;

  char* w = (char*)d_ws;
  auto alloc = [&](size_t bytes) {
    char* p = w;
    w += (bytes + 255) & ~(size_t)255;
    return p;
  };
  // region A: xb (bf16 x); dead after k_aggx
  char* regA = alloc((size_t)N * 128 * sizeof(unsigned short));  // 12.8 MB
  unsigned short* xb = (unsigned short*)regA;
  // region B: avgxb (bf16); dead after gemm_head -> h2b at offset 0,
  // w2s at offset 25.6 MB.
  char* regB = alloc((size_t)N * 512 * sizeof(unsigned short));  // 51.2 MB
  unsigned short* avgxb = (unsigned short*)regB;
  unsigned short* h2b = (unsigned short*)regB;
  float* w2s = (float*)(regB + (size_t)N * 256 * sizeof(unsigned short));
  // region C: w1s (26.4 MB), dead before k_gemm_head writes hact1 (51.2 MB).
  char* regC = alloc((size_t)N * 256 * 4);                       // 51.2 MB
  float* hact1 = (float*)regC;
  float4* w1s = (float4*)regC;
  float* s_src1  = (float*)alloc((size_t)N * 4 * 4);
  float* s_dst1  = (float*)alloc((size_t)N * 4 * 4);
  float* s2_src  = (float*)alloc((size_t)N * 4);
  float* s2_dst  = (float*)alloc((size_t)N * 4);
  float* va      = (float*)alloc(128 * 8 * 4);
  int* count     = (int*)alloc((size_t)N * 4);
  int* cursor    = (int*)alloc((size_t)N * 4);
  int* row_ptr   = (int*)alloc((size_t)(N + 1) * 4);
  int* src_sorted= (int*)alloc((size_t)Etot * 4);
  int* dst_sorted= (int*)alloc((size_t)Etot * 4);

  hipMemsetAsync(count, 0, (size_t)N * 4, stream);

  // ---- layer 1 (h1 never materialized) ----
  k_vproj<<<4, 256, 0, stream>>>(W1, a_src1, a_dst1, va);
  k_cast<<<(N * 128 / 8 + 255) / 256, 256, 0, stream>>>(x, xb, N * 128 / 8);
  k_scores_x<<<(N + 3) / 4, 256, 0, stream>>>(x, va, s_src1, s_dst1, N);
  k_degree<<<(Etot + 255) / 256, 256, 0, stream>>>(ei, E, Etot, count);
  k_scan<<<1, 1024, 0, stream>>>(count, row_ptr, cursor, N);
  k_scatter<<<(Etot + 255) / 256, 256, 0, stream>>>(ei, E, Etot, cursor,
                                                    s_src1, s_dst1,
                                                    src_sorted, dst_sorted, w1s);
  k_aggx<<<(N + 3) / 4, 256, 0, stream>>>(xb, row_ptr, src_sorted, w1s, avgxb, N);
  dim3 g1((N + BM - 1) / BM, 1, 4);
  k_gemm_head<<<g1, 256, 0, stream>>>(avgxb, W1, b1, hact1, N);

  // ---- layer 2 ----
  k_gemm2<<<(N + BM - 1) / BM, 256, 0, stream>>>(hact1, W2, h2b, N);
  k_scores2<<<(N + 3) / 4, 256, 0, stream>>>(h2b, a_src2, a_dst2, s2_src, s2_dst, N);
  k_w2<<<(Etot + 255) / 256, 256, 0, stream>>>(src_sorted, dst_sorted,
                                               s2_src, s2_dst, w2s, Etot);
  k_agg2<<<(N + 3) / 4, 256, 0, stream>>>(h2b, row_ptr, src_sorted, w2s,
                                          b2, Wout, bout, logits, N);
}